// Round 12
// baseline (391.748 us; speedup 1.0000x reference)
//
#include <hip/hip_runtime.h>

#define D 64
#define LN_EPS 1e-5f
#define ALPHA 0.5f

#define GSH 8            // log2(nodes per bucket) = 256-node buckets
#define GBN 256
#define TILE 1024        // edges per scatter block
#define RPB  (2*TILE)    // records per block region (exact capacity)
#define CAPQ 1792        // per quarter-bucket sorted capacity (mean ~1536)
#define MAXB 400         // bucket array pad (nbuck = 391)
#define WZB 2048         // wzux-role blocks in the fused front kernel

typedef float vf4 __attribute__((ext_vector_type(4)));

// f32 -> bf16 round-to-nearest-even
__device__ __forceinline__ unsigned short f2bf(float f) {
    unsigned u = __float_as_uint(f);
    u += 0x7FFF + ((u >> 16) & 1);
    return (unsigned short)(u >> 16);
}
// bf16 -> f32
__device__ __forceinline__ float bf2f(unsigned short h) {
    return __uint_as_float(((unsigned)h) << 16);
}

// DPP rotate-add within a 16-lane row: v += row_ror<N>(v). VALU-only.
template <int CTRL>
__device__ __forceinline__ float dpp_rotadd(float v) {
    int p = __builtin_amdgcn_update_dpp(0, __float_as_int(v), CTRL, 0xF, 0xF, true);
    return v + __int_as_float(p);
}

// ---------------- Fused front: local-sort scatter  ||  WzUx ----------------
// Blocks [0, sb): per-block counting sort of 2048 edge records -> dense
// coalesced flush into a private region; segment offsets to boffs. ZERO
// global atomics, exact capacity, no overflow path.
// Blocks [sb, sb+WZB): WzUx = nf*(z@W.T + deg*(x@U.T + Ub)) -> bf16, with
// weights PINNED in VGPRs (asm keep-alive defeats the remat-from-L1 the
// compiler chose at VGPR_Count=52).
__global__ __launch_bounds__(256) void front_kernel(
    const int* __restrict__ row, const int* __restrict__ col,
    int* __restrict__ boffs, int* __restrict__ data,
    int E, int nbuck, int sb,
    const float* __restrict__ z, const float* __restrict__ x,
    const float* __restrict__ nf, const float* __restrict__ W,
    const float* __restrict__ Uw, const float* __restrict__ Ub,
    unsigned short* __restrict__ wzux, int N)
{
    __shared__ int cnt[MAXB];
    __shared__ int scn[MAXB + 8];
    __shared__ int rbuf[RPB];
    const int t = threadIdx.x;

    if ((int)blockIdx.x < sb) {
        // ---------------- scatter role ----------------
        const int e0 = blockIdx.x * TILE;
        const int e1 = min(e0 + TILE, E);

        int rr[4], cc[4];
#pragma unroll
        for (int k = 0; k < 4; ++k) {
            int e = e0 + t + k * 256;
            bool ok = e < e1;
            rr[k] = ok ? row[e] : -1;
            cc[k] = ok ? col[e] : -1;
        }

        for (int i = t; i < nbuck; i += 256) cnt[i] = 0;
        __syncthreads();

#pragma unroll
        for (int k = 0; k < 4; ++k) {
            if (rr[k] >= 0) {
                atomicAdd(&cnt[rr[k] >> GSH], 1);
                atomicAdd(&cnt[cc[k] >> GSH], 1);
            }
        }
        __syncthreads();

        // exclusive scan of cnt[0..nbuck-1] -> scn[0..nbuck] by wave 0
        if (t < 64) {
            int base = t * 7;
            int loc[7]; int s = 0;
#pragma unroll
            for (int j = 0; j < 7; ++j) {
                int b = base + j;
                int v = (b < nbuck) ? cnt[b] : 0;
                loc[j] = s; s += v;
            }
            int inc = s;
#pragma unroll
            for (int off = 1; off < 64; off <<= 1) {
                int u = __shfl_up(inc, off);
                if (t >= off) inc += u;
            }
            int excl = inc - s;
#pragma unroll
            for (int j = 0; j < 7; ++j) {
                int b = base + j;
                if (b <= nbuck) scn[b] = excl + loc[j];
            }
        }
        __syncthreads();

        // segment offsets (absolute into data) + local cursors
        const int rbase = blockIdx.x * RPB;
        for (int b = t; b <= nbuck; b += 256)
            boffs[blockIdx.x * (nbuck + 1) + b] = rbase + scn[b];
        for (int b = t; b < nbuck; b += 256) cnt[b] = scn[b];
        __syncthreads();

        // place into LDS rbuf (capacity exact: total <= RPB)
#pragma unroll
        for (int k = 0; k < 4; ++k) {
            int r = rr[k], c = cc[k];
            if (r >= 0) {
                rbuf[atomicAdd(&cnt[r >> GSH], 1)] =
                    (c << 9) | ((r & (GBN - 1)) << 1);
                rbuf[atomicAdd(&cnt[c >> GSH], 1)] =
                    (r << 9) | ((c & (GBN - 1)) << 1) | 1;
            }
        }
        __syncthreads();

        // dense coalesced flush
        const int total = scn[nbuck];
        for (int i = t; i < total; i += 256) data[rbase + i] = rbuf[i];
    } else {
        // ---------------- wzux role (dim-split, bf16 out, pinned weights) ---
        const int wb   = blockIdx.x - sb;
        const int lane = t & 63;
        const int wid  = t >> 6;
        const int par   = (wb >> 3) & 1;                 // XCD-paired parity
        const int chunk = (wb & 7) | ((wb >> 4) << 3);   // [0, WZB/2)
        const int half = lane >> 5;               // 0: W/z, 1: U/x
        const int d    = par * 32 + (lane & 31);  // output dim

        const float* M = half ? Uw : W;
        vf4 wreg[16];
        {
            const vf4* wr = (const vf4*)(M + (size_t)d * D);
#pragma unroll
            for (int i = 0; i < 16; ++i) wreg[i] = wr[i];
        }
        const float ub = Ub[d];
        const float* base_src = half ? x : z;

        const int start = chunk * 4 + wid;
        const int step  = (WZB >> 1) * 4;

        for (int n = start; n < N; n += step) {
            // pin the weight tile in VGPRs: "+v" forbids remat-from-memory
#pragma unroll
            for (int i = 0; i < 16; ++i)
                asm volatile("" : "+v"(wreg[i]));

            const int un = __builtin_amdgcn_readfirstlane(n);
            const vf4* src = (const vf4*)(base_src + (size_t)un * D);
            float a0 = 0.f, a1 = 0.f, a2 = 0.f, a3 = 0.f;
#pragma unroll
            for (int c = 0; c < 16; ++c) {
                vf4 v = src[c];
                a0 = fmaf(v.x, wreg[c].x, a0);
                a1 = fmaf(v.y, wreg[c].y, a1);
                a2 = fmaf(v.z, wreg[c].z, a2);
                a3 = fmaf(v.w, wreg[c].w, a3);
            }
            float acc = (a0 + a1) + (a2 + a3);
            float other = __shfl_xor(acc, 32);    // partner lane shares d
            if (half == 0) {
                float nfv = nf[un];
                float deg = (nfv > 0.f) ? (1.f / nfv) : 0.f;
                wzux[(size_t)un * D + d] = f2bf(nfv * (acc + deg * (other + ub)));
            }
        }
    }
}

// ---------------- Quarter-bucket sort + register aggregation ---------------
// One block per 64 nodes (quarter of a 256-node bucket). Gather the bucket's
// records from the per-scatter-block segments (boffs), counting-sort into
// LDS, then one wave per node accumulates newz in registers (4 edges in
// parallel, 4 gathers in flight, DPP allreduce). Row written once.
__global__ __launch_bounds__(256) void bucket_sort_agg_kernel(
    const unsigned short* __restrict__ wzux,
    const int* __restrict__ boffs, const int* __restrict__ data,
    int nblk, int nbuck,
    const float* __restrict__ nf,
    const float4* __restrict__ gamma4, const float4* __restrict__ beta4,
    float4* __restrict__ out4, int N)
{
    __shared__ int sorted[CAPQ];
    __shared__ int offs[65];
    __shared__ int curs[64];

    const int blk    = blockIdx.x;       // 64-node group
    const int base   = blk << 6;
    const int cntN   = min(64, N - base);
    const int bucket = blk >> 2;
    const int q      = blk & 3;
    const int t      = threadIdx.x;

    if (t < 65) offs[t] = 0;
    __syncthreads();

    // count (filtered by quarter) over per-block segments
    for (int b = t; b < nblk; b += 256) {
        const int* bo = &boffs[b * (nbuck + 1) + bucket];
        int s0 = bo[0], s1 = bo[1];
        for (int i = s0; i < s1; ++i) {
            int l8 = (data[i] >> 1) & (GBN - 1);
            if ((l8 >> 6) == q) atomicAdd(&offs[(l8 & 63) + 1], 1);
        }
    }
    __syncthreads();

    // inclusive scan of offs[1..64] by wave 0
    if (t < 64) {
        int v = offs[t + 1];
#pragma unroll
        for (int off = 1; off < 64; off <<= 1) {
            int u = __shfl_up(v, off);
            if (t >= off) v += u;
        }
        offs[t + 1] = v;
    }
    __syncthreads();
    if (t < 64) curs[t] = offs[t];
    __syncthreads();

    // place
    for (int b = t; b < nblk; b += 256) {
        const int* bo = &boffs[b * (nbuck + 1) + bucket];
        int s0 = bo[0], s1 = bo[1];
        for (int i = s0; i < s1; ++i) {
            int rec = data[i];
            int l8 = (rec >> 1) & (GBN - 1);
            if ((l8 >> 6) == q) {
                int pos = atomicAdd(&curs[l8 & 63], 1);
                if (pos < CAPQ) sorted[pos] = rec;
            }
        }
    }
    __syncthreads();

    // register aggregation: wave wid handles locals wid, wid+4, ...
    const int lane = t & 63;
    const int wid  = t >> 6;
    const int g = lane >> 4;      // edge slot within wave
    const int l = lane & 15;      // float4 slot within row
    const float4 gm = gamma4[l];
    const float4 bt = beta4[l];
    const ushort4* wz4 = (const ushort4*)wzux;   // row = 16 slots of 8B

    for (int local = wid; local < cntN; local += 4) {
        const int s = min(offs[local], CAPQ);
        const int e = min(offs[local + 1], CAPQ);
        const int n = base + local;
        ushort4 sh = wz4[n * 16 + l];
        const float4 self = make_float4(bf2f(sh.x), bf2f(sh.y),
                                        bf2f(sh.z), bf2f(sh.w));
        float4 acc = make_float4(0.f, 0.f, 0.f, 0.f);

#define PROC2(ENT, H)                                                        \
        {                                                                    \
            int ent = (ENT);                                                 \
            float sgn = (ent & 1) ? -1.f : 1.f;                              \
            float4 o = make_float4(bf2f((H).x), bf2f((H).y),                 \
                                   bf2f((H).z), bf2f((H).w));                \
            float r0 = fmaxf(sgn * (self.x - o.x), 0.f);                     \
            float r1 = fmaxf(sgn * (self.y - o.y), 0.f);                     \
            float r2 = fmaxf(sgn * (self.z - o.z), 0.f);                     \
            float r3 = fmaxf(sgn * (self.w - o.w), 0.f);                     \
            float ss = r0 + r1 + r2 + r3;                                    \
            float sq = r0 * r0 + r1 * r1 + r2 * r2 + r3 * r3;                \
            ss = dpp_rotadd<0x128>(ss);  sq = dpp_rotadd<0x128>(sq);         \
            ss = dpp_rotadd<0x124>(ss);  sq = dpp_rotadd<0x124>(sq);         \
            ss = dpp_rotadd<0x122>(ss);  sq = dpp_rotadd<0x122>(sq);         \
            ss = dpp_rotadd<0x121>(ss);  sq = dpp_rotadd<0x121>(sq);         \
            float mu   = ss * (1.f / 64.f);                                  \
            float var  = sq * (1.f / 64.f) - mu * mu;                        \
            float rstd = rsqrtf(var + LN_EPS);                               \
            acc.x += sgn * ((r0 - mu) * rstd * gm.x + bt.x);                 \
            acc.y += sgn * ((r1 - mu) * rstd * gm.y + bt.y);                 \
            acc.z += sgn * ((r2 - mu) * rstd * gm.z + bt.z);                 \
            acc.w += sgn * ((r3 - mu) * rstd * gm.w + bt.w);                 \
        }

        int i = s + g;
        for (; i + 12 < e; i += 16) {
            // 4 gathers in flight before any LN computation
            int e0 = sorted[i];
            int e1 = sorted[i + 4];
            int e2 = sorted[i + 8];
            int e3 = sorted[i + 12];
            ushort4 h0 = wz4[(e0 >> 9) * 16 + l];
            ushort4 h1 = wz4[(e1 >> 9) * 16 + l];
            ushort4 h2 = wz4[(e2 >> 9) * 16 + l];
            ushort4 h3 = wz4[(e3 >> 9) * 16 + l];
            PROC2(e0, h0);
            PROC2(e1, h1);
            PROC2(e2, h2);
            PROC2(e3, h3);
        }
        for (; i < e; i += 4) {
            int e0 = sorted[i];
            ushort4 h0 = wz4[(e0 >> 9) * 16 + l];
            PROC2(e0, h0);
        }
#undef PROC2

        // butterfly across the 4 edge slots (allreduce)
#pragma unroll
        for (int m = 16; m < 64; m <<= 1) {
            acc.x += __shfl_xor(acc.x, m);
            acc.y += __shfl_xor(acc.y, m);
            acc.z += __shfl_xor(acc.z, m);
            acc.w += __shfl_xor(acc.w, m);
        }

        if (g == 0) {
            float nfv = nf[n];
            out4[n * 16 + l] = make_float4(acc.x * nfv, acc.y * nfv,
                                           acc.z * nfv, acc.w * nfv);
        }
    }
}

// ---------------- Stage 3: out = ALPHA*(-(newz@W)) + (1-ALPHA)*z ----------
__global__ __launch_bounds__(256) void out_kernel(
    const float* accv, const float* __restrict__ z,
    const float* __restrict__ W, float* out, int N)
{
    const int lane = threadIdx.x & 63;
    const int wid  = threadIdx.x >> 6;

    float wcol[D];   // wcol[k] = W[k][lane]
#pragma unroll
    for (int k = 0; k < D; ++k) wcol[k] = W[k * D + lane];

    for (int n = blockIdx.x * 4 + wid; n < N; n += gridDim.x * 4) {
        const int un = __builtin_amdgcn_readfirstlane(n);
        const float4* ar = (const float4*)(accv + (size_t)un * D);
        float a0 = 0.f, a1 = 0.f, a2 = 0.f, a3 = 0.f;
#pragma unroll
        for (int c = 0; c < 16; ++c) {
            float4 a = ar[c];
            a0 = fmaf(a.x, wcol[c * 4 + 0], a0);
            a1 = fmaf(a.y, wcol[c * 4 + 1], a1);
            a2 = fmaf(a.z, wcol[c * 4 + 2], a2);
            a3 = fmaf(a.w, wcol[c * 4 + 3], a3);
        }
        float acc = (a0 + a1) + (a2 + a3);
        out[(size_t)un * D + lane] =
            (1.0f - ALPHA) * z[(size_t)un * D + lane] - ALPHA * acc;
    }
}

extern "C" void kernel_launch(void* const* d_in, const int* in_sizes, int n_in,
                              void* d_out, int out_size, void* d_ws, size_t ws_size,
                              hipStream_t stream) {
    const float* z     = (const float*)d_in[0];
    const float* x     = (const float*)d_in[1];
    const int*   ei    = (const int*)d_in[2];
    const float* nf    = (const float*)d_in[3];
    const float* W     = (const float*)d_in[4];
    const float* Uw    = (const float*)d_in[5];
    const float* Ub    = (const float*)d_in[6];
    const float* gamma = (const float*)d_in[7];
    const float* beta  = (const float*)d_in[8];

    const int N = in_sizes[0] / D;      // 100000
    const int E = in_sizes[2] / 2;      // 1200000
    const int nbuck = (N + GBN - 1) >> GSH;          // 391
    const int sb = (E + TILE - 1) / TILE;            // 1172 scatter blocks

    float* out = (float*)d_out;

    // ---- workspace layout ----
    char* ws = (char*)d_ws;
    size_t off = 0;
    auto alloc = [&](size_t bytes) {
        char* p = ws + off;
        off += (bytes + 255) & ~(size_t)255;
        return p;
    };
    unsigned short* wzux = (unsigned short*)alloc((size_t)N * D * 2);        // 12.8 MB
    int* boffs = (int*)alloc((size_t)sb * (nbuck + 1) * sizeof(int));        // 1.84 MB
    int* data  = (int*)alloc((size_t)sb * RPB * sizeof(int));                // 9.6 MB

    front_kernel<<<sb + WZB, 256, 0, stream>>>(
        ei, ei + E, boffs, data, E, nbuck, sb,
        z, x, nf, W, Uw, Ub, wzux, N);

    int ab = (N + 63) / 64;
    bucket_sort_agg_kernel<<<ab, 256, 0, stream>>>(
        wzux, boffs, data, sb, nbuck, nf,
        (const float4*)gamma, (const float4*)beta,
        (float4*)out, N);

    out_kernel<<<2048, 256, 0, stream>>>(out, z, W, out, N);
}

// Round 13
// 341.201 us; speedup vs baseline: 1.1481x; 1.1481x over previous
//
#include <hip/hip_runtime.h>

#define D 64
#define LN_EPS 1e-5f
#define ALPHA 0.5f

#define GSH 8            // log2(nodes per bucket) = 256-node buckets
#define GBN 256
#define NSUB 8           // per-XCD sub-regions
#define TILE 2048        // edges per radix-scatter block
#define CAPS 1280        // per (bucket,xcd) region capacity (mean ~768)
#define CAPQ 1792        // per quarter-bucket sorted capacity (mean ~1536)
#define OVF_CAP 131072
#define MAXBUCK 400
#define WZB 2048         // wzux-role blocks in the fused front kernel

typedef float vf4 __attribute__((ext_vector_type(4)));

// wave-uniform XCD id (0..7) on gfx950
__device__ __forceinline__ unsigned xcc_id() {
    unsigned v;
    asm volatile("s_getreg_b32 %0, hwreg(HW_REG_XCC_ID)" : "=s"(v));
    return v & (NSUB - 1);
}

// f32 -> bf16 round-to-nearest-even
__device__ __forceinline__ unsigned short f2bf(float f) {
    unsigned u = __float_as_uint(f);
    u += 0x7FFF + ((u >> 16) & 1);
    return (unsigned short)(u >> 16);
}
// bf16 -> f32
__device__ __forceinline__ float bf2f(unsigned short h) {
    return __uint_as_float(((unsigned)h) << 16);
}

// DPP rotate-add within a 16-lane row: v += row_ror<N>(v). VALU-only.
template <int CTRL>
__device__ __forceinline__ float dpp_rotadd(float v) {
    int p = __builtin_amdgcn_update_dpp(0, __float_as_int(v), CTRL, 0xF, 0xF, true);
    return v + __int_as_float(p);
}

// ---------------- Fused front: radix scatter  ||  WzUx transform -----------
// Blocks [0, sb): block-aggregated radix scatter of edge records.
// Blocks [sb, sb+WZB): WzUx = nf * (z@W.T + deg*(x@U.T + Ub)) -> bf16,
// weights PINNED in VGPRs (asm keep-alive defeats remat-from-L1; R11's
// VGPR_Count=52 proved the 64-VGPR weight tile was being reloaded per node).
__global__ __launch_bounds__(256) void front_kernel(
    const int* __restrict__ row, const int* __restrict__ col,
    int* __restrict__ gcur, int* __restrict__ data,
    int* __restrict__ ovf_cnt, int2* __restrict__ ovf,
    int E, int nbuck, int sb,
    const float* __restrict__ z, const float* __restrict__ x,
    const float* __restrict__ nf, const float* __restrict__ W,
    const float* __restrict__ Uw, const float* __restrict__ Ub,
    unsigned short* __restrict__ wzux, int N)
{
    __shared__ int cnt[MAXBUCK];
    __shared__ int gbase[MAXBUCK];
    const int t = threadIdx.x;

    if ((int)blockIdx.x < sb) {
        // ---------------- radix scatter role ----------------
        const int e0 = blockIdx.x * TILE;
        const int e1 = min(e0 + TILE, E);
        const unsigned sub = xcc_id();

        for (int i = t; i < nbuck; i += 256) cnt[i] = 0;
        __syncthreads();

        for (int e = e0 + t; e < e1; e += 256) {
            atomicAdd(&cnt[row[e] >> GSH], 1);
            atomicAdd(&cnt[col[e] >> GSH], 1);
        }
        __syncthreads();

        for (int b = t; b < nbuck; b += 256) {
            int c = cnt[b];
            gbase[b] = (c > 0) ? atomicAdd(&gcur[b * NSUB + sub], c) : 0;
        }
        __syncthreads();

        for (int e = e0 + t; e < e1; e += 256) {
            int r = row[e], c = col[e];
            {
                int b = r >> GSH;
                int s = atomicSub(&cnt[b], 1) - 1;
                int pos = gbase[b] + s;
                int rec = (c << 9) | ((r & (GBN - 1)) << 1);
                if (pos < CAPS) data[(b * NSUB + (int)sub) * CAPS + pos] = rec;
                else { int o = atomicAdd(ovf_cnt, 1);
                       if (o < OVF_CAP) ovf[o] = make_int2(b, rec); }
            }
            {
                int b = c >> GSH;
                int s = atomicSub(&cnt[b], 1) - 1;
                int pos = gbase[b] + s;
                int rec = (r << 9) | ((c & (GBN - 1)) << 1) | 1;
                if (pos < CAPS) data[(b * NSUB + (int)sub) * CAPS + pos] = rec;
                else { int o = atomicAdd(ovf_cnt, 1);
                       if (o < OVF_CAP) ovf[o] = make_int2(b, rec); }
            }
        }
    } else {
        // ---------------- wzux role (dim-split, bf16 out, pinned weights) ---
        const int wb   = blockIdx.x - sb;
        const int lane = t & 63;
        const int wid  = t >> 6;
        const int par   = (wb >> 3) & 1;                 // XCD-paired parity
        const int chunk = (wb & 7) | ((wb >> 4) << 3);   // [0, WZB/2)
        const int half = lane >> 5;               // 0: W/z, 1: U/x
        const int d    = par * 32 + (lane & 31);  // output dim

        const float* M = half ? Uw : W;
        vf4 wreg[16];
        {
            const vf4* wr = (const vf4*)(M + (size_t)d * D);
#pragma unroll
            for (int i = 0; i < 16; ++i) wreg[i] = wr[i];
        }
        const float ub = Ub[d];
        const float* base_src = half ? x : z;

        const int start = chunk * 4 + wid;
        const int step  = (WZB >> 1) * 4;

        for (int n = start; n < N; n += step) {
            // pin the weight tile in VGPRs each iteration
#pragma unroll
            for (int i = 0; i < 16; ++i)
                asm volatile("" : "+v"(wreg[i]));

            const int un = __builtin_amdgcn_readfirstlane(n);
            const vf4* src = (const vf4*)(base_src + (size_t)un * D);
            float a0 = 0.f, a1 = 0.f, a2 = 0.f, a3 = 0.f;
#pragma unroll
            for (int c = 0; c < 16; ++c) {
                vf4 v = src[c];
                a0 = fmaf(v.x, wreg[c].x, a0);
                a1 = fmaf(v.y, wreg[c].y, a1);
                a2 = fmaf(v.z, wreg[c].z, a2);
                a3 = fmaf(v.w, wreg[c].w, a3);
            }
            float acc = (a0 + a1) + (a2 + a3);
            float other = __shfl_xor(acc, 32);    // partner lane shares d
            if (half == 0) {
                float nfv = nf[un];
                float deg = (nfv > 0.f) ? (1.f / nfv) : 0.f;
                wzux[(size_t)un * D + d] = f2bf(nfv * (acc + deg * (other + ub)));
            }
        }
    }
}

// ---------------- Quarter-bucket sort + register aggregation ---------------
// One block per 64 nodes (quarter of a 256-node bucket). Counting-sort the
// filtered records into LDS, then one wave per node accumulates newz in
// registers (4 edges in parallel per wave, 4 gathers in flight). Per-edge
// mean/var reduction is DPP rotate-allreduce (VALU pipe only).
__global__ __launch_bounds__(256) void bucket_sort_agg_kernel(
    const unsigned short* __restrict__ wzux,
    const int* __restrict__ gcur, const int* __restrict__ data,
    const int* __restrict__ ovf_cnt, const int2* __restrict__ ovf,
    const float* __restrict__ nf,
    const float4* __restrict__ gamma4, const float4* __restrict__ beta4,
    float4* __restrict__ out4, int N)
{
    __shared__ int sorted[CAPQ];
    __shared__ int offs[65];
    __shared__ int curs[64];

    const int blk    = blockIdx.x;       // 64-node group
    const int base   = blk << 6;
    const int cntN   = min(64, N - base);
    const int bucket = blk >> 2;
    const int q      = blk & 3;
    const int t      = threadIdx.x;

    if (t < 65) offs[t] = 0;
    __syncthreads();

    const int ocnt = min(*ovf_cnt, OVF_CAP);

    // count (filtered by quarter)
    for (int sub = 0; sub < NSUB; ++sub) {
        const int cs = min(gcur[bucket * NSUB + sub], CAPS);
        const int* p = &data[(bucket * NSUB + sub) * CAPS];
        for (int i = t; i < cs; i += 256) {
            int l8 = (p[i] >> 1) & (GBN - 1);
            if ((l8 >> 6) == q) atomicAdd(&offs[(l8 & 63) + 1], 1);
        }
    }
    for (int i = t; i < ocnt; i += 256) {
        int2 v = ovf[i];
        int l8 = (v.y >> 1) & (GBN - 1);
        if (v.x == bucket && (l8 >> 6) == q) atomicAdd(&offs[(l8 & 63) + 1], 1);
    }
    __syncthreads();

    // inclusive scan of offs[1..64] by wave 0
    if (t < 64) {
        int v = offs[t + 1];
#pragma unroll
        for (int off = 1; off < 64; off <<= 1) {
            int u = __shfl_up(v, off);
            if (t >= off) v += u;
        }
        offs[t + 1] = v;
    }
    __syncthreads();
    if (t < 64) curs[t] = offs[t];
    __syncthreads();

    // place
    for (int sub = 0; sub < NSUB; ++sub) {
        const int cs = min(gcur[bucket * NSUB + sub], CAPS);
        const int* p = &data[(bucket * NSUB + sub) * CAPS];
        for (int i = t; i < cs; i += 256) {
            int rec = p[i];
            int l8 = (rec >> 1) & (GBN - 1);
            if ((l8 >> 6) == q) {
                int pos = atomicAdd(&curs[l8 & 63], 1);
                if (pos < CAPQ) sorted[pos] = rec;
            }
        }
    }
    for (int i = t; i < ocnt; i += 256) {
        int2 v = ovf[i];
        int l8 = (v.y >> 1) & (GBN - 1);
        if (v.x == bucket && (l8 >> 6) == q) {
            int pos = atomicAdd(&curs[l8 & 63], 1);
            if (pos < CAPQ) sorted[pos] = v.y;
        }
    }
    __syncthreads();

    // register aggregation: wave wid handles locals wid, wid+4, ...
    const int lane = t & 63;
    const int wid  = t >> 6;
    const int g = lane >> 4;      // edge slot within wave
    const int l = lane & 15;      // float4 slot within row
    const float4 gm = gamma4[l];
    const float4 bt = beta4[l];
    const ushort4* wz4 = (const ushort4*)wzux;   // row = 16 slots of 8B

    for (int local = wid; local < cntN; local += 4) {
        const int s = min(offs[local], CAPQ);
        const int e = min(offs[local + 1], CAPQ);
        const int n = base + local;
        ushort4 sh = wz4[n * 16 + l];
        const float4 self = make_float4(bf2f(sh.x), bf2f(sh.y),
                                        bf2f(sh.z), bf2f(sh.w));
        float4 acc = make_float4(0.f, 0.f, 0.f, 0.f);

#define PROC2(ENT, H)                                                        \
        {                                                                    \
            int ent = (ENT);                                                 \
            float sgn = (ent & 1) ? -1.f : 1.f;                              \
            float4 o = make_float4(bf2f((H).x), bf2f((H).y),                 \
                                   bf2f((H).z), bf2f((H).w));                \
            float r0 = fmaxf(sgn * (self.x - o.x), 0.f);                     \
            float r1 = fmaxf(sgn * (self.y - o.y), 0.f);                     \
            float r2 = fmaxf(sgn * (self.z - o.z), 0.f);                     \
            float r3 = fmaxf(sgn * (self.w - o.w), 0.f);                     \
            float ss = r0 + r1 + r2 + r3;                                    \
            float sq = r0 * r0 + r1 * r1 + r2 * r2 + r3 * r3;                \
            ss = dpp_rotadd<0x128>(ss);  sq = dpp_rotadd<0x128>(sq);         \
            ss = dpp_rotadd<0x124>(ss);  sq = dpp_rotadd<0x124>(sq);         \
            ss = dpp_rotadd<0x122>(ss);  sq = dpp_rotadd<0x122>(sq);         \
            ss = dpp_rotadd<0x121>(ss);  sq = dpp_rotadd<0x121>(sq);         \
            float mu   = ss * (1.f / 64.f);                                  \
            float var  = sq * (1.f / 64.f) - mu * mu;                        \
            float rstd = rsqrtf(var + LN_EPS);                               \
            acc.x += sgn * ((r0 - mu) * rstd * gm.x + bt.x);                 \
            acc.y += sgn * ((r1 - mu) * rstd * gm.y + bt.y);                 \
            acc.z += sgn * ((r2 - mu) * rstd * gm.z + bt.z);                 \
            acc.w += sgn * ((r3 - mu) * rstd * gm.w + bt.w);                 \
        }

        int i = s + g;
        for (; i + 12 < e; i += 16) {
            // 4 gathers in flight before any LN computation
            int e0 = sorted[i];
            int e1 = sorted[i + 4];
            int e2 = sorted[i + 8];
            int e3 = sorted[i + 12];
            ushort4 h0 = wz4[(e0 >> 9) * 16 + l];
            ushort4 h1 = wz4[(e1 >> 9) * 16 + l];
            ushort4 h2 = wz4[(e2 >> 9) * 16 + l];
            ushort4 h3 = wz4[(e3 >> 9) * 16 + l];
            PROC2(e0, h0);
            PROC2(e1, h1);
            PROC2(e2, h2);
            PROC2(e3, h3);
        }
        for (; i < e; i += 4) {
            int e0 = sorted[i];
            ushort4 h0 = wz4[(e0 >> 9) * 16 + l];
            PROC2(e0, h0);
        }
#undef PROC2

        // butterfly across the 4 edge slots (allreduce)
#pragma unroll
        for (int m = 16; m < 64; m <<= 1) {
            acc.x += __shfl_xor(acc.x, m);
            acc.y += __shfl_xor(acc.y, m);
            acc.z += __shfl_xor(acc.z, m);
            acc.w += __shfl_xor(acc.w, m);
        }

        if (g == 0) {
            float nfv = nf[n];
            out4[n * 16 + l] = make_float4(acc.x * nfv, acc.y * nfv,
                                           acc.z * nfv, acc.w * nfv);
        }
    }
}

// ---------------- Stage 3: out = ALPHA*(-(newz@W)) + (1-ALPHA)*z ----------
// Lane d holds W[:,d] in VGPRs; newz row via wave-uniform float4 loads.
// In place on d_out (each row read fully by its owner wave before its store).
__global__ __launch_bounds__(256) void out_kernel(
    const float* accv, const float* __restrict__ z,
    const float* __restrict__ W, float* out, int N)
{
    const int lane = threadIdx.x & 63;
    const int wid  = threadIdx.x >> 6;

    float wcol[D];   // wcol[k] = W[k][lane]
#pragma unroll
    for (int k = 0; k < D; ++k) wcol[k] = W[k * D + lane];

    for (int n = blockIdx.x * 4 + wid; n < N; n += gridDim.x * 4) {
        const int un = __builtin_amdgcn_readfirstlane(n);
        const float4* ar = (const float4*)(accv + (size_t)un * D);
        float a0 = 0.f, a1 = 0.f, a2 = 0.f, a3 = 0.f;
#pragma unroll
        for (int c = 0; c < 16; ++c) {
            float4 a = ar[c];
            a0 = fmaf(a.x, wcol[c * 4 + 0], a0);
            a1 = fmaf(a.y, wcol[c * 4 + 1], a1);
            a2 = fmaf(a.z, wcol[c * 4 + 2], a2);
            a3 = fmaf(a.w, wcol[c * 4 + 3], a3);
        }
        float acc = (a0 + a1) + (a2 + a3);
        out[(size_t)un * D + lane] =
            (1.0f - ALPHA) * z[(size_t)un * D + lane] - ALPHA * acc;
    }
}

extern "C" void kernel_launch(void* const* d_in, const int* in_sizes, int n_in,
                              void* d_out, int out_size, void* d_ws, size_t ws_size,
                              hipStream_t stream) {
    const float* z     = (const float*)d_in[0];
    const float* x     = (const float*)d_in[1];
    const int*   ei    = (const int*)d_in[2];
    const float* nf    = (const float*)d_in[3];
    const float* W     = (const float*)d_in[4];
    const float* Uw    = (const float*)d_in[5];
    const float* Ub    = (const float*)d_in[6];
    const float* gamma = (const float*)d_in[7];
    const float* beta  = (const float*)d_in[8];

    const int N = in_sizes[0] / D;      // 100000
    const int E = in_sizes[2] / 2;      // 1200000
    const int nbuck = (N + GBN - 1) >> GSH;          // 391
    const int sb = (E + TILE - 1) / TILE;            // 586 scatter blocks

    float* out = (float*)d_out;

    // ---- workspace layout ----
    char* ws = (char*)d_ws;
    size_t off = 0;
    auto alloc = [&](size_t bytes) {
        char* p = ws + off;
        off += (bytes + 255) & ~(size_t)255;
        return p;
    };
    unsigned short* wzux = (unsigned short*)alloc((size_t)N * D * 2);           // 12.8 MB
    int*   gcur    = (int*)  alloc((size_t)nbuck * NSUB * sizeof(int));         // 12.5 KB
    int*   ovf_cnt = (int*)  alloc(sizeof(int));
    int*   data    = (int*)  alloc((size_t)nbuck * NSUB * CAPS * sizeof(int));  // 16 MB
    int2*  ovf     = (int2*) alloc((size_t)OVF_CAP * sizeof(int2));             // 1 MB

    hipMemsetAsync(gcur, 0, (size_t)nbuck * NSUB * sizeof(int), stream);
    hipMemsetAsync(ovf_cnt, 0, sizeof(int), stream);

    front_kernel<<<sb + WZB, 256, 0, stream>>>(
        ei, ei + E, gcur, data, ovf_cnt, ovf, E, nbuck, sb,
        z, x, nf, W, Uw, Ub, wzux, N);

    int ab = (N + 63) / 64;
    bucket_sort_agg_kernel<<<ab, 256, 0, stream>>>(
        wzux, gcur, data, ovf_cnt, ovf, nf,
        (const float4*)gamma, (const float4*)beta,
        (float4*)out, N);

    out_kernel<<<2048, 256, 0, stream>>>(out, z, W, out, N);
}

// Round 14
// 331.659 us; speedup vs baseline: 1.1812x; 1.0288x over previous
//
#include <hip/hip_runtime.h>

#define D 64
#define LN_EPS 1e-5f
#define ALPHA 0.5f

#define GSH 8            // log2(nodes per bucket) = 256-node buckets
#define GBN 256
#define NSUB 8           // per-XCD sub-regions
#define TILE 2048        // edges per radix-scatter block
#define CAPS 1280        // per (bucket,xcd) region capacity (mean ~768); 1280*4B = 5120B (16B-aligned regions)
#define CAPQ 1792        // per quarter-bucket sorted capacity (mean ~1536)
#define OVF_CAP 131072
#define MAXBUCK 400
#define WZB 2048         // wzux-role blocks in the fused front kernel

typedef float vf4 __attribute__((ext_vector_type(4)));

// wave-uniform XCD id (0..7) on gfx950
__device__ __forceinline__ unsigned xcc_id() {
    unsigned v;
    asm volatile("s_getreg_b32 %0, hwreg(HW_REG_XCC_ID)" : "=s"(v));
    return v & (NSUB - 1);
}

// f32 -> bf16 round-to-nearest-even
__device__ __forceinline__ unsigned short f2bf(float f) {
    unsigned u = __float_as_uint(f);
    u += 0x7FFF + ((u >> 16) & 1);
    return (unsigned short)(u >> 16);
}
// bf16 -> f32
__device__ __forceinline__ float bf2f(unsigned short h) {
    return __uint_as_float(((unsigned)h) << 16);
}

// DPP rotate-add within a 16-lane row: v += row_ror<N>(v). VALU-only.
template <int CTRL>
__device__ __forceinline__ float dpp_rotadd(float v) {
    int p = __builtin_amdgcn_update_dpp(0, __float_as_int(v), CTRL, 0xF, 0xF, true);
    return v + __int_as_float(p);
}

// ---------------- Fused front: radix scatter  ||  WzUx transform -----------
// Blocks [0, sb): block-aggregated radix scatter, int4-vectorized edge loads
// in both the count and place passes (4x fewer VMEM issues).
// Blocks [sb, sb+WZB): WzUx = nf * (z@W.T + deg*(x@U.T + Ub)) -> bf16.
// (R13 note: asm VGPR pin was a measured null; removed.)
__global__ __launch_bounds__(256) void front_kernel(
    const int* __restrict__ row, const int* __restrict__ col,
    int* __restrict__ gcur, int* __restrict__ data,
    int* __restrict__ ovf_cnt, int2* __restrict__ ovf,
    int E, int nbuck, int sb,
    const float* __restrict__ z, const float* __restrict__ x,
    const float* __restrict__ nf, const float* __restrict__ W,
    const float* __restrict__ Uw, const float* __restrict__ Ub,
    unsigned short* __restrict__ wzux, int N)
{
    __shared__ int cnt[MAXBUCK];
    __shared__ int gbase[MAXBUCK];
    const int t = threadIdx.x;

    if ((int)blockIdx.x < sb) {
        // ---------------- radix scatter role ----------------
        const int e0 = blockIdx.x * TILE;
        const int e1 = min(e0 + TILE, E);
        const int m  = e1 - e0;
        const int nv4 = m >> 2;
        const unsigned sub = xcc_id();
        const int4* r4 = (const int4*)(row + e0);
        const int4* c4 = (const int4*)(col + e0);

        for (int i = t; i < nbuck; i += 256) cnt[i] = 0;
        __syncthreads();

        // count pass (vectorized)
        for (int i = t; i < nv4; i += 256) {
            int4 rr = r4[i], cc = c4[i];
            atomicAdd(&cnt[rr.x >> GSH], 1); atomicAdd(&cnt[cc.x >> GSH], 1);
            atomicAdd(&cnt[rr.y >> GSH], 1); atomicAdd(&cnt[cc.y >> GSH], 1);
            atomicAdd(&cnt[rr.z >> GSH], 1); atomicAdd(&cnt[cc.z >> GSH], 1);
            atomicAdd(&cnt[rr.w >> GSH], 1); atomicAdd(&cnt[cc.w >> GSH], 1);
        }
        for (int e = e0 + (nv4 << 2) + t; e < e1; e += 256) {
            atomicAdd(&cnt[row[e] >> GSH], 1);
            atomicAdd(&cnt[col[e] >> GSH], 1);
        }
        __syncthreads();

        for (int b = t; b < nbuck; b += 256) {
            int c = cnt[b];
            gbase[b] = (c > 0) ? atomicAdd(&gcur[b * NSUB + sub], c) : 0;
        }
        __syncthreads();

        // place pass (vectorized)
#define PLACE(RN, CN)                                                        \
        {                                                                    \
            int r_ = (RN), c_ = (CN);                                        \
            {                                                                \
                int b = r_ >> GSH;                                           \
                int s = atomicSub(&cnt[b], 1) - 1;                           \
                int pos = gbase[b] + s;                                      \
                int rec = (c_ << 9) | ((r_ & (GBN - 1)) << 1);               \
                if (pos < CAPS) data[(b * NSUB + (int)sub) * CAPS + pos] = rec; \
                else { int o = atomicAdd(ovf_cnt, 1);                        \
                       if (o < OVF_CAP) ovf[o] = make_int2(b, rec); }        \
            }                                                                \
            {                                                                \
                int b = c_ >> GSH;                                           \
                int s = atomicSub(&cnt[b], 1) - 1;                           \
                int pos = gbase[b] + s;                                      \
                int rec = (r_ << 9) | ((c_ & (GBN - 1)) << 1) | 1;           \
                if (pos < CAPS) data[(b * NSUB + (int)sub) * CAPS + pos] = rec; \
                else { int o = atomicAdd(ovf_cnt, 1);                        \
                       if (o < OVF_CAP) ovf[o] = make_int2(b, rec); }        \
            }                                                                \
        }
        for (int i = t; i < nv4; i += 256) {
            int4 rr = r4[i], cc = c4[i];
            PLACE(rr.x, cc.x);
            PLACE(rr.y, cc.y);
            PLACE(rr.z, cc.z);
            PLACE(rr.w, cc.w);
        }
        for (int e = e0 + (nv4 << 2) + t; e < e1; e += 256) {
            PLACE(row[e], col[e]);
        }
#undef PLACE
    } else {
        // ---------------- wzux role (dim-split, bf16 output) ----------------
        const int wb   = blockIdx.x - sb;
        const int lane = t & 63;
        const int wid  = t >> 6;
        const int par   = (wb >> 3) & 1;                 // XCD-paired parity
        const int chunk = (wb & 7) | ((wb >> 4) << 3);   // [0, WZB/2)
        const int half = lane >> 5;               // 0: W/z, 1: U/x
        const int d    = par * 32 + (lane & 31);  // output dim

        const float* M = half ? Uw : W;
        vf4 wreg[16];
        {
            const vf4* wr = (const vf4*)(M + (size_t)d * D);
#pragma unroll
            for (int i = 0; i < 16; ++i) wreg[i] = wr[i];
        }
        const float ub = Ub[d];
        const float* base_src = half ? x : z;

        const int start = chunk * 4 + wid;
        const int step  = (WZB >> 1) * 4;

        for (int n = start; n < N; n += step) {
            const int un = __builtin_amdgcn_readfirstlane(n);
            const vf4* src = (const vf4*)(base_src + (size_t)un * D);
            float a0 = 0.f, a1 = 0.f, a2 = 0.f, a3 = 0.f;
#pragma unroll
            for (int c = 0; c < 16; ++c) {
                vf4 v = src[c];
                a0 = fmaf(v.x, wreg[c].x, a0);
                a1 = fmaf(v.y, wreg[c].y, a1);
                a2 = fmaf(v.z, wreg[c].z, a2);
                a3 = fmaf(v.w, wreg[c].w, a3);
            }
            float acc = (a0 + a1) + (a2 + a3);
            float other = __shfl_xor(acc, 32);    // partner lane shares d
            if (half == 0) {
                float nfv = nf[un];
                float deg = (nfv > 0.f) ? (1.f / nfv) : 0.f;
                wzux[(size_t)un * D + d] = f2bf(nfv * (acc + deg * (other + ub)));
            }
        }
    }
}

// ---------------- Quarter-bucket sort + register aggregation ---------------
// One block per 64 nodes (quarter of a 256-node bucket). Count/place passes
// over the bucket's (bucket,sub) regions are int4-vectorized. One wave per
// node accumulates newz in registers (4 edges in parallel per wave, depth-4
// then depth-2 pipelined gathers, DPP allreduce). Row written once.
__global__ __launch_bounds__(256) void bucket_sort_agg_kernel(
    const unsigned short* __restrict__ wzux,
    const int* __restrict__ gcur, const int* __restrict__ data,
    const int* __restrict__ ovf_cnt, const int2* __restrict__ ovf,
    const float* __restrict__ nf,
    const float4* __restrict__ gamma4, const float4* __restrict__ beta4,
    float4* __restrict__ out4, int N)
{
    __shared__ int sorted[CAPQ];
    __shared__ int offs[65];
    __shared__ int curs[64];

    const int blk    = blockIdx.x;       // 64-node group
    const int base   = blk << 6;
    const int cntN   = min(64, N - base);
    const int bucket = blk >> 2;
    const int q      = blk & 3;
    const int t      = threadIdx.x;

    if (t < 65) offs[t] = 0;
    __syncthreads();

    const int ocnt = min(*ovf_cnt, OVF_CAP);

#define CNT1(REC)                                                            \
    { int l8 = ((REC) >> 1) & (GBN - 1);                                     \
      if ((l8 >> 6) == q) atomicAdd(&offs[(l8 & 63) + 1], 1); }

    // count pass (vectorized)
    for (int sub = 0; sub < NSUB; ++sub) {
        const int cs  = min(gcur[bucket * NSUB + sub], CAPS);
        const int* p  = &data[(bucket * NSUB + sub) * CAPS];
        const int4* p4 = (const int4*)p;
        const int nv4 = cs >> 2;
        for (int i = t; i < nv4; i += 256) {
            int4 r = p4[i];
            CNT1(r.x); CNT1(r.y); CNT1(r.z); CNT1(r.w);
        }
        for (int i = (nv4 << 2) + t; i < cs; i += 256) CNT1(p[i]);
    }
    for (int i = t; i < ocnt; i += 256) {
        int2 v = ovf[i];
        if (v.x == bucket) CNT1(v.y);
    }
#undef CNT1
    __syncthreads();

    // inclusive scan of offs[1..64] by wave 0
    if (t < 64) {
        int v = offs[t + 1];
#pragma unroll
        for (int off = 1; off < 64; off <<= 1) {
            int u = __shfl_up(v, off);
            if (t >= off) v += u;
        }
        offs[t + 1] = v;
    }
    __syncthreads();
    if (t < 64) curs[t] = offs[t];
    __syncthreads();

#define PUT1(REC)                                                            \
    { int rec_ = (REC); int l8 = (rec_ >> 1) & (GBN - 1);                    \
      if ((l8 >> 6) == q) {                                                  \
          int pos = atomicAdd(&curs[l8 & 63], 1);                            \
          if (pos < CAPQ) sorted[pos] = rec_; } }

    // place pass (vectorized)
    for (int sub = 0; sub < NSUB; ++sub) {
        const int cs  = min(gcur[bucket * NSUB + sub], CAPS);
        const int* p  = &data[(bucket * NSUB + sub) * CAPS];
        const int4* p4 = (const int4*)p;
        const int nv4 = cs >> 2;
        for (int i = t; i < nv4; i += 256) {
            int4 r = p4[i];
            PUT1(r.x); PUT1(r.y); PUT1(r.z); PUT1(r.w);
        }
        for (int i = (nv4 << 2) + t; i < cs; i += 256) PUT1(p[i]);
    }
    for (int i = t; i < ocnt; i += 256) {
        int2 v = ovf[i];
        if (v.x == bucket) PUT1(v.y);
    }
#undef PUT1
    __syncthreads();

    // register aggregation: wave wid handles locals wid, wid+4, ...
    const int lane = t & 63;
    const int wid  = t >> 6;
    const int g = lane >> 4;      // edge slot within wave
    const int l = lane & 15;      // float4 slot within row
    const float4 gm = gamma4[l];
    const float4 bt = beta4[l];
    const ushort4* wz4 = (const ushort4*)wzux;   // row = 16 slots of 8B

    for (int local = wid; local < cntN; local += 4) {
        const int s = min(offs[local], CAPQ);
        const int e = min(offs[local + 1], CAPQ);
        const int n = base + local;
        ushort4 sh = wz4[n * 16 + l];
        const float4 self = make_float4(bf2f(sh.x), bf2f(sh.y),
                                        bf2f(sh.z), bf2f(sh.w));
        float4 acc = make_float4(0.f, 0.f, 0.f, 0.f);

#define PROC2(ENT, H)                                                        \
        {                                                                    \
            int ent = (ENT);                                                 \
            float sgn = (ent & 1) ? -1.f : 1.f;                              \
            float4 o = make_float4(bf2f((H).x), bf2f((H).y),                 \
                                   bf2f((H).z), bf2f((H).w));                \
            float r0 = fmaxf(sgn * (self.x - o.x), 0.f);                     \
            float r1 = fmaxf(sgn * (self.y - o.y), 0.f);                     \
            float r2 = fmaxf(sgn * (self.z - o.z), 0.f);                     \
            float r3 = fmaxf(sgn * (self.w - o.w), 0.f);                     \
            float ss = r0 + r1 + r2 + r3;                                    \
            float sq = r0 * r0 + r1 * r1 + r2 * r2 + r3 * r3;                \
            ss = dpp_rotadd<0x128>(ss);  sq = dpp_rotadd<0x128>(sq);         \
            ss = dpp_rotadd<0x124>(ss);  sq = dpp_rotadd<0x124>(sq);         \
            ss = dpp_rotadd<0x122>(ss);  sq = dpp_rotadd<0x122>(sq);         \
            ss = dpp_rotadd<0x121>(ss);  sq = dpp_rotadd<0x121>(sq);         \
            float mu   = ss * (1.f / 64.f);                                  \
            float var  = sq * (1.f / 64.f) - mu * mu;                        \
            float rstd = rsqrtf(var + LN_EPS);                               \
            acc.x += sgn * ((r0 - mu) * rstd * gm.x + bt.x);                 \
            acc.y += sgn * ((r1 - mu) * rstd * gm.y + bt.y);                 \
            acc.z += sgn * ((r2 - mu) * rstd * gm.z + bt.z);                 \
            acc.w += sgn * ((r3 - mu) * rstd * gm.w + bt.w);                 \
        }

        int i = s + g;
        for (; i + 12 < e; i += 16) {
            // 4 gathers in flight
            int e0 = sorted[i];
            int e1 = sorted[i + 4];
            int e2 = sorted[i + 8];
            int e3 = sorted[i + 12];
            ushort4 h0 = wz4[(e0 >> 9) * 16 + l];
            ushort4 h1 = wz4[(e1 >> 9) * 16 + l];
            ushort4 h2 = wz4[(e2 >> 9) * 16 + l];
            ushort4 h3 = wz4[(e3 >> 9) * 16 + l];
            PROC2(e0, h0);
            PROC2(e1, h1);
            PROC2(e2, h2);
            PROC2(e3, h3);
        }
        if (i + 4 < e) {
            // depth-2 tail (covers the common remainder in one wait)
            int e0 = sorted[i];
            int e1 = sorted[i + 4];
            ushort4 h0 = wz4[(e0 >> 9) * 16 + l];
            ushort4 h1 = wz4[(e1 >> 9) * 16 + l];
            PROC2(e0, h0);
            PROC2(e1, h1);
            i += 8;
        }
        if (i < e) {
            int e0 = sorted[i];
            ushort4 h0 = wz4[(e0 >> 9) * 16 + l];
            PROC2(e0, h0);
        }
#undef PROC2

        // butterfly across the 4 edge slots (allreduce)
#pragma unroll
        for (int m = 16; m < 64; m <<= 1) {
            acc.x += __shfl_xor(acc.x, m);
            acc.y += __shfl_xor(acc.y, m);
            acc.z += __shfl_xor(acc.z, m);
            acc.w += __shfl_xor(acc.w, m);
        }

        if (g == 0) {
            float nfv = nf[n];
            out4[n * 16 + l] = make_float4(acc.x * nfv, acc.y * nfv,
                                           acc.z * nfv, acc.w * nfv);
        }
    }
}

// ---------------- Stage 3: out = ALPHA*(-(newz@W)) + (1-ALPHA)*z ----------
// Lane d holds W[:,d] in VGPRs; newz row via wave-uniform float4 loads.
// In place on d_out (each row read fully by its owner wave before its store).
__global__ __launch_bounds__(256) void out_kernel(
    const float* accv, const float* __restrict__ z,
    const float* __restrict__ W, float* out, int N)
{
    const int lane = threadIdx.x & 63;
    const int wid  = threadIdx.x >> 6;

    float wcol[D];   // wcol[k] = W[k][lane]
#pragma unroll
    for (int k = 0; k < D; ++k) wcol[k] = W[k * D + lane];

    for (int n = blockIdx.x * 4 + wid; n < N; n += gridDim.x * 4) {
        const int un = __builtin_amdgcn_readfirstlane(n);
        const float4* ar = (const float4*)(accv + (size_t)un * D);
        float a0 = 0.f, a1 = 0.f, a2 = 0.f, a3 = 0.f;
#pragma unroll
        for (int c = 0; c < 16; ++c) {
            float4 a = ar[c];
            a0 = fmaf(a.x, wcol[c * 4 + 0], a0);
            a1 = fmaf(a.y, wcol[c * 4 + 1], a1);
            a2 = fmaf(a.z, wcol[c * 4 + 2], a2);
            a3 = fmaf(a.w, wcol[c * 4 + 3], a3);
        }
        float acc = (a0 + a1) + (a2 + a3);
        out[(size_t)un * D + lane] =
            (1.0f - ALPHA) * z[(size_t)un * D + lane] - ALPHA * acc;
    }
}

extern "C" void kernel_launch(void* const* d_in, const int* in_sizes, int n_in,
                              void* d_out, int out_size, void* d_ws, size_t ws_size,
                              hipStream_t stream) {
    const float* z     = (const float*)d_in[0];
    const float* x     = (const float*)d_in[1];
    const int*   ei    = (const int*)d_in[2];
    const float* nf    = (const float*)d_in[3];
    const float* W     = (const float*)d_in[4];
    const float* Uw    = (const float*)d_in[5];
    const float* Ub    = (const float*)d_in[6];
    const float* gamma = (const float*)d_in[7];
    const float* beta  = (const float*)d_in[8];

    const int N = in_sizes[0] / D;      // 100000
    const int E = in_sizes[2] / 2;      // 1200000
    const int nbuck = (N + GBN - 1) >> GSH;          // 391
    const int sb = (E + TILE - 1) / TILE;            // 586 scatter blocks

    float* out = (float*)d_out;

    // ---- workspace layout ----
    char* ws = (char*)d_ws;
    size_t off = 0;
    auto alloc = [&](size_t bytes) {
        char* p = ws + off;
        off += (bytes + 255) & ~(size_t)255;
        return p;
    };
    unsigned short* wzux = (unsigned short*)alloc((size_t)N * D * 2);           // 12.8 MB
    int*   curblk  = (int*)  alloc(((size_t)nbuck * NSUB + 64) * sizeof(int));  // gcur + ovf_cnt
    int*   data    = (int*)  alloc((size_t)nbuck * NSUB * CAPS * sizeof(int));  // 16 MB
    int2*  ovf     = (int2*) alloc((size_t)OVF_CAP * sizeof(int2));             // 1 MB

    int* gcur    = curblk;
    int* ovf_cnt = curblk + (size_t)nbuck * NSUB;

    // single memset covers gcur and ovf_cnt
    hipMemsetAsync(curblk, 0, ((size_t)nbuck * NSUB + 64) * sizeof(int), stream);

    front_kernel<<<sb + WZB, 256, 0, stream>>>(
        ei, ei + E, gcur, data, ovf_cnt, ovf, E, nbuck, sb,
        z, x, nf, W, Uw, Ub, wzux, N);

    int ab = (N + 63) / 64;
    bucket_sort_agg_kernel<<<ab, 256, 0, stream>>>(
        wzux, gcur, data, ovf_cnt, ovf, nf,
        (const float4*)gamma, (const float4*)beta,
        (float4*)out, N);

    out_kernel<<<2048, 256, 0, stream>>>(out, z, W, out, N);
}